// Round 10
// baseline (254.580 us; speedup 1.0000x reference)
//
#include <hip/hip_runtime.h>
#include <stdint.h>
#include <stddef.h>

#define Tq 2048
#define DM 1024

typedef unsigned short u16;
typedef __bf16 bf16x8 __attribute__((ext_vector_type(8)));
typedef float f32x4 __attribute__((ext_vector_type(4)));
typedef unsigned short u16x8 __attribute__((ext_vector_type(8)));
typedef unsigned short u16x4 __attribute__((ext_vector_type(4)));

__device__ __forceinline__ float bf2f(u16 h) {
    union { unsigned int u; float f; } c; c.u = ((unsigned int)h) << 16; return c.f;
}
__device__ __forceinline__ u16 f2bf(float f) {
    union { float f; unsigned int u; } c; c.f = f;
    unsigned int u = c.u;
    return (u16)((u + 0x7fffu + ((u >> 16) & 1u)) >> 16);  // RNE
}

// bare v_exp_f32 (2^x) — exp2f expands to the guarded __ocml sequence.
__device__ __forceinline__ float exp2_native(float x) {
    float r; asm("v_exp_f32 %0, %1" : "=v"(r) : "v"(x)); return r;
}

// async global->LDS, 16B per lane; lds base wave-uniform (HW adds lane*16)
#define GLD(gp, lp) __builtin_amdgcn_global_load_lds(                                  \
        (const __attribute__((address_space(1))) void*)(gp),                           \
        (__attribute__((address_space(3))) void*)(lp), 16, 0, 0)

// ---------------------------------------------------------------------------
// Format sniff (round-3 proven).
// ---------------------------------------------------------------------------
__device__ __forceinline__ int sniff_fp32(const u16* xs) {
    const int lane = threadIdx.x & 63;
    const u16 u = xs[lane];
    const int e = (u >> 7) & 0xFF;
    unsigned long long m = __ballot(e >= 160);
    return __popcll(m) >= 4;
}

__device__ __forceinline__ void cvt_body(const void* src, u16* dst, int i0, int fmt) {
    if (fmt) {
        const float* s = (const float*)src;
        float4 a = *(const float4*)(s + i0);
        float4 b = *(const float4*)(s + i0 + 4);
        u16x8 o;
        o[0] = f2bf(a.x); o[1] = f2bf(a.y); o[2] = f2bf(a.z); o[3] = f2bf(a.w);
        o[4] = f2bf(b.x); o[5] = f2bf(b.y); o[6] = f2bf(b.z); o[7] = f2bf(b.w);
        *(u16x8*)(dst + i0) = o;
    } else {
        *(u16x8*)(dst + i0) = *(const u16x8*)((const u16*)src + i0);
    }
}

// ---------------------------------------------------------------------------
// Fused canonicalization: x (blocks 0..4095) + 4 weights/biases (4096..6143).
// ---------------------------------------------------------------------------
__global__ void cvt_all(const void* __restrict__ x,
                        const void* s0, const void* s1, const void* s2, const void* s3,
                        const void* t0, const void* t1, const void* t2, const void* t3,
                        u16* __restrict__ xc, u16* __restrict__ dstW, float* __restrict__ dstB,
                        const u16* __restrict__ xs, int* flag) {
    const int fmt = sniff_fp32(xs);
    int bx = blockIdx.x;
    if (bx < 4096) {
        if (bx == 0 && threadIdx.x == 0) *flag = fmt;
        const int i0 = (bx * 256 + threadIdx.x) * 8;
        cvt_body(x, xc, i0, fmt);
    } else {
        bx -= 4096;
        const int wsel = bx >> 9;          // 0..3
        const int bi   = bx & 511;
        const void* s = (wsel == 0) ? s0 : (wsel == 1) ? s1 : (wsel == 2) ? s2 : s3;
        u16* d = dstW + (size_t)wsel * (DM * DM);
        const int i0 = (bi * 256 + threadIdx.x) * 8;
        cvt_body(s, d, i0, fmt);
        if (bi == 0) {                     // bias piggybacked
            const void* bs = (wsel == 0) ? t0 : (wsel == 1) ? t1 : (wsel == 2) ? t2 : t3;
            float* db = dstB + (size_t)wsel * DM;
            const int j0 = threadIdx.x * 4;
            if (fmt) {
                *(float4*)(db + j0) = *(const float4*)((const float*)bs + j0);
            } else {
                const u16* ss = (const u16*)bs;
                db[j0+0] = bf2f(ss[j0+0]); db[j0+1] = bf2f(ss[j0+1]);
                db[j0+2] = bf2f(ss[j0+2]); db[j0+3] = bf2f(ss[j0+3]);
            }
        }
    }
}

#define NT 16   // K / 64

// ---------------------------------------------------------------------------
// GEMM v4 "gemm256q" (round 10, mode-0 only): BM=BN=256, BK=64, 512 thr /
// 8 waves (2M x 4N), wave tile 128x64, acc[8][4]. LDS dbuf 2 x 64 KB = 128 KB.
// K-loop = 4 C-quadrant phases (rh x ch), each 16 MFMA over full K=64:
//   p0 (rh0,ch0): af(rh0) 8 reads + bfr(ch0) 4    [vmcnt(4) + s_barrier]
//   p1 (rh0,ch1): bfr(ch1) 4                      [stage AO(t+1)]
//   p2 (rh1,ch1): af(rh1) 8                       [vmcnt(8) + s_barrier; stage AE(t+2)]
//   p3 (rh1,ch0): bfr(ch0) 4
// AE (chunks a0+a2 = rh0 rows of both wm halves) dies after p1 -> AE(t+2) is
// staged into the LIVE buffer at p2, fenced by p2's barrier. B(t+1)/AO(t+1)
// go to the dead buffer at p0/p1. Leads: 4-6 phases each.
// Sync uses RAW s_barrier + per-wave counted vmcnt — __syncthreads drains
// vmcnt(0) before s_barrier (round-8 lesson), defeating T4.
// FIFO-derived gates: before p0 need B(t): newer = AO(t)[2]+AE(t+1)[2] ->
// vmcnt(4) (2 at t=NT-1); before p2 need AO(t): newer = AE(t+1)[2]+B(t+1)[4]
// +AO(t+1)[2] -> vmcnt(8) (0 at t=NT-1 only). All phase ds_reads feed MFMAs
// in the same phase => retired before the next barrier.
// ---------------------------------------------------------------------------
__global__ __launch_bounds__(512, 1) void gemm256q(
    const u16* __restrict__ A,
    const u16* __restrict__ W0, const u16* __restrict__ W1, const u16* __restrict__ W2,
    const float* __restrict__ b0, const float* __restrict__ b1, const float* __restrict__ b2,
    u16* o0, u16* o1, u16* o2)
{
    __shared__ u16 LB[2][32768];   // per buf: A elems [0,16384), B [16384,32768)

    const int K = DM;
    const int j = blockIdx.y;          // 0..11
    const int which = j >> 2;
    const u16* Wp     = (which == 0) ? W0 : (which == 1) ? W1 : W2;
    const float* bias = (which == 0) ? b0 : (which == 1) ? b1 : b2;
    u16* out          = (which == 0) ? o0 : (which == 1) ? o1 : o2;
    const int jn = j & 3;
    const int m0 = blockIdx.x * 256, n0 = jn * 256;

    const int tid  = threadIdx.x;
    const int w    = tid >> 6, lane = tid & 63;
    const int wm   = w >> 2, wn = w & 3;
    const int l4   = lane & 15, quad = lane >> 4;
    const int rsub = lane >> 3;                       // 0..7
    const int colE = ((lane & 7) ^ rsub) << 3;        // swizzled source column (elems)

    // chunk = 64 rows x 64 cols = 8 KB, one GLD instruction (512 x 16B).
#define SAC(kt, bf, ci) do {                                                            \
        const int row_ = (ci) * 64 + w * 8 + rsub;                                      \
        GLD(A + (size_t)(m0 + row_) * K + (kt) * 64 + colE,                             \
            (char*)&LB[bf][0] + (ci) * 8192 + w * 1024); } while (0)
#define SBC(kt, bf, ci) do {                                                            \
        const int row_ = (ci) * 64 + w * 8 + rsub;                                      \
        GLD(Wp + (size_t)(n0 + row_) * K + (kt) * 64 + colE,                            \
            (char*)&LB[bf][0] + 32768 + (ci) * 8192 + w * 1024); } while (0)
#define SAE(kt, bf)   do { SAC(kt, bf, 0); SAC(kt, bf, 2); } while (0)
#define SAO(kt, bf)   do { SAC(kt, bf, 1); SAC(kt, bf, 3); } while (0)
#define SBALL(kt, bf) do { SBC(kt, bf, 0); SBC(kt, bf, 1); SBC(kt, bf, 2); SBC(kt, bf, 3); } while (0)

    f32x4 acc[8][4] = {};

    // prologue, FIFO order mirrors steady state: AE(0), B(0), AO(0), AE(1)
    SAE(0, 0); SBALL(0, 0); SAO(0, 0); SAE(1, 1);

    const int swz = (l4 & 7) << 3;

    for (int t = 0; t < NT; ++t) {
        const int cur = t & 1;
        const u16* Ab = &LB[cur][0];
        const u16* Bb = &LB[cur][16384];
        const bool s1 = (t + 1 < NT);
        const bool s2 = (t + 2 < NT);

        bf16x8 af[4][2], bfr[2][2];

        // ================= p0: (rh0, ch0) =================
        if (s1) asm volatile("s_waitcnt vmcnt(4)" ::: "memory");
        else    asm volatile("s_waitcnt vmcnt(2)" ::: "memory");
        __builtin_amdgcn_s_barrier();
        if (s1) SBALL(t + 1, cur ^ 1);
#pragma unroll
        for (int i = 0; i < 4; ++i)
#pragma unroll
            for (int kc = 0; kc < 2; ++kc)
                af[i][kc] = *(const bf16x8*)&Ab[(wm * 128 + i * 16 + l4) * 64 + ((kc * 32 + quad * 8) ^ swz)];
#pragma unroll
        for (int jj = 0; jj < 2; ++jj)
#pragma unroll
            for (int kc = 0; kc < 2; ++kc)
                bfr[jj][kc] = *(const bf16x8*)&Bb[(wn * 64 + jj * 16 + l4) * 64 + ((kc * 32 + quad * 8) ^ swz)];
        __builtin_amdgcn_s_setprio(1);
#pragma unroll
        for (int i = 0; i < 4; ++i)
#pragma unroll
            for (int jj = 0; jj < 2; ++jj)
#pragma unroll
                for (int kc = 0; kc < 2; ++kc)
                    acc[i][jj] = __builtin_amdgcn_mfma_f32_16x16x32_bf16(af[i][kc], bfr[jj][kc], acc[i][jj], 0, 0, 0);
        __builtin_amdgcn_s_setprio(0);

        // ================= p1: (rh0, ch1) =================
        if (s1) SAO(t + 1, cur ^ 1);
#pragma unroll
        for (int jj = 0; jj < 2; ++jj)
#pragma unroll
            for (int kc = 0; kc < 2; ++kc)
                bfr[jj][kc] = *(const bf16x8*)&Bb[(wn * 64 + 32 + jj * 16 + l4) * 64 + ((kc * 32 + quad * 8) ^ swz)];
        __builtin_amdgcn_s_setprio(1);
#pragma unroll
        for (int i = 0; i < 4; ++i)
#pragma unroll
            for (int jj = 0; jj < 2; ++jj)
#pragma unroll
                for (int kc = 0; kc < 2; ++kc)
                    acc[i][2 + jj] = __builtin_amdgcn_mfma_f32_16x16x32_bf16(af[i][kc], bfr[jj][kc], acc[i][2 + jj], 0, 0, 0);
        __builtin_amdgcn_s_setprio(0);

        // ================= p2: (rh1, ch1) =================
        if (s1) asm volatile("s_waitcnt vmcnt(8)" ::: "memory");
        else    asm volatile("s_waitcnt vmcnt(0)" ::: "memory");
        __builtin_amdgcn_s_barrier();              // fences p0/p1 reads of AE
        if (s2) SAE(t + 2, cur);                   // overwrite dead AE region
#pragma unroll
        for (int i = 0; i < 4; ++i)
#pragma unroll
            for (int kc = 0; kc < 2; ++kc)
                af[i][kc] = *(const bf16x8*)&Ab[(wm * 128 + 64 + i * 16 + l4) * 64 + ((kc * 32 + quad * 8) ^ swz)];
        __builtin_amdgcn_s_setprio(1);
#pragma unroll
        for (int i = 0; i < 4; ++i)
#pragma unroll
            for (int jj = 0; jj < 2; ++jj)
#pragma unroll
                for (int kc = 0; kc < 2; ++kc)
                    acc[4 + i][2 + jj] = __builtin_amdgcn_mfma_f32_16x16x32_bf16(af[i][kc], bfr[jj][kc], acc[4 + i][2 + jj], 0, 0, 0);
        __builtin_amdgcn_s_setprio(0);

        // ================= p3: (rh1, ch0) =================
#pragma unroll
        for (int jj = 0; jj < 2; ++jj)
#pragma unroll
            for (int kc = 0; kc < 2; ++kc)
                bfr[jj][kc] = *(const bf16x8*)&Bb[(wn * 64 + jj * 16 + l4) * 64 + ((kc * 32 + quad * 8) ^ swz)];
        __builtin_amdgcn_s_setprio(1);
#pragma unroll
        for (int i = 0; i < 4; ++i)
#pragma unroll
            for (int jj = 0; jj < 2; ++jj)
#pragma unroll
                for (int kc = 0; kc < 2; ++kc)
                    acc[4 + i][jj] = __builtin_amdgcn_mfma_f32_16x16x32_bf16(af[i][kc], bfr[jj][kc], acc[4 + i][jj], 0, 0, 0);
        __builtin_amdgcn_s_setprio(0);
    }
#undef SAC
#undef SBC
#undef SAE
#undef SAO
#undef SBALL

    const float SCQ = 0.18033688011112042f;    // log2(e)/sqrt(64), folded into Q

#pragma unroll
    for (int ni = 0; ni < 4; ++ni) {
        const int colw = n0 + wn * 64 + ni * 16 + l4;
        const float bv = bias[colw];
        const int h = colw >> 6, d = colw & 63;
#pragma unroll
        for (int mi = 0; mi < 8; ++mi) {
            const int mb = m0 + wm * 128 + mi * 16 + quad * 4;
            const int bb = mb >> 11, t0 = mb & 2047;
            if (which == 2) {
                // V -> (B,H,64,T) transposed store, 4 consecutive t per 8B
                u16x4 pk;
#pragma unroll
                for (int reg = 0; reg < 4; ++reg) pk[reg] = f2bf(acc[mi][ni][reg] + bv);
                *(u16x4*)&out[((size_t)(bb * 16 + h) * 64 + d) * 2048 + t0] = pk;
            } else {
                const float s = (which == 0) ? SCQ : 1.0f;
#pragma unroll
                for (int reg = 0; reg < 4; ++reg)
                    out[(size_t)((bb * 16 + h) * 2048 + (t0 + reg)) * 64 + d] =
                        f2bf((acc[mi][ni][reg] + bv) * s);
            }
        }
    }
}

// ---------------------------------------------------------------------------
// GEMM v3 (round 8, proven) — retained VERBATIM for the output projection
// (mode 1). BM=128 x BN=256, triple-buffered LDS, T3 interleave.
// ---------------------------------------------------------------------------
__global__ __launch_bounds__(512, 1) void gemm256(
    const u16* __restrict__ A,
    const u16* __restrict__ W0, const u16* __restrict__ W1, const u16* __restrict__ W2,
    const float* __restrict__ b0, const float* __restrict__ b1, const float* __restrict__ b2,
    u16* o0, u16* o1, u16* o2,
    const int* __restrict__ flag, int mode)
{
    __shared__ u16 LB[3][24576];

    const int K = DM;
    const int j = blockIdx.y;
    const int which = (mode == 0) ? (j >> 2) : 0;
    const u16* Wp     = (which == 0) ? W0 : (which == 1) ? W1 : W2;
    const float* bias = (which == 0) ? b0 : (which == 1) ? b1 : b2;
    u16* out          = (which == 0) ? o0 : (which == 1) ? o1 : o2;
    const int jn = (mode == 0) ? (j & 3) : j;
    const int m0 = blockIdx.x * 128, n0 = jn * 256;

    const int tid  = threadIdx.x;
    const int w    = tid >> 6, lane = tid & 63;
    const int wm   = w >> 2, wn = w & 3;
    const int l4   = lane & 15, quad = lane >> 4;
    const int rsub = lane >> 3;
    const int colE = ((lane & 7) ^ rsub) << 3;

#define STAGE_A(kt, bf) do {                                                            \
        const int k0s = (kt) * 64;                                                      \
        _Pragma("unroll")                                                               \
        for (int c = 0; c < 2; ++c) {                                                   \
            const int row = c * 64 + w * 8 + rsub;                                      \
            GLD(A + (size_t)(m0 + row) * K + k0s + colE,                                \
                (char*)&LB[bf][0] + c * 8192 + w * 1024);                               \
        }                                                                               \
        {   const int row = w * 8 + rsub;                                               \
            GLD(Wp + (size_t)(n0 + row) * K + k0s + colE,                               \
                (char*)&LB[bf][0] + 16384 + w * 1024); }                                \
    } while (0)
#define STAGE_B(kt, bf) do {                                                            \
        const int k0s = (kt) * 64;                                                      \
        _Pragma("unroll")                                                               \
        for (int c = 1; c < 4; ++c) {                                                   \
            const int row = c * 64 + w * 8 + rsub;                                      \
            GLD(Wp + (size_t)(n0 + row) * K + k0s + colE,                               \
                (char*)&LB[bf][0] + 16384 + c * 8192 + w * 1024);                       \
        }                                                                               \
    } while (0)

    f32x4 acc[4][4] = {};

    STAGE_A(0, 0); STAGE_B(0, 0);
    STAGE_A(1, 1); STAGE_B(1, 1);
    asm volatile("s_waitcnt vmcnt(6)" ::: "memory");
    __syncthreads();

    for (int t = 0; t < NT; ++t) {
        const int cur = t % 3;
        const int nxt = (t + 2) % 3;
        const u16* Ab = &LB[cur][0];
        const u16* Bb = &LB[cur][8192];
        const int swz = (l4 & 7) << 3;
        const bool pf = (t + 2 < NT);

        if (pf) STAGE_A(t + 2, nxt);
        {
            bf16x8 af[4], bfr[4];
            const int kq = (quad * 8) ^ swz;
#pragma unroll
            for (int m = 0; m < 4; ++m)
                af[m] = *(const bf16x8*)&Ab[(wm * 64 + m * 16 + l4) * 64 + kq];
#pragma unroll
            for (int n = 0; n < 4; ++n)
                bfr[n] = *(const bf16x8*)&Bb[(wn * 64 + n * 16 + l4) * 64 + kq];
            __builtin_amdgcn_s_setprio(1);
#pragma unroll
            for (int m = 0; m < 4; ++m)
#pragma unroll
                for (int n = 0; n < 4; ++n)
                    acc[m][n] = __builtin_amdgcn_mfma_f32_16x16x32_bf16(af[m], bfr[n], acc[m][n], 0, 0, 0);
            __builtin_amdgcn_s_setprio(0);
        }

        if (pf) STAGE_B(t + 2, nxt);
        {
            bf16x8 af[4], bfr[4];
            const int kq = (32 + quad * 8) ^ swz;
#pragma unroll
            for (int m = 0; m < 4; ++m)
                af[m] = *(const bf16x8*)&Ab[(wm * 64 + m * 16 + l4) * 64 + kq];
#pragma unroll
            for (int n = 0; n < 4; ++n)
                bfr[n] = *(const bf16x8*)&Bb[(wn * 64 + n * 16 + l4) * 64 + kq];
            __builtin_amdgcn_s_setprio(1);
#pragma unroll
            for (int m = 0; m < 4; ++m)
#pragma unroll
                for (int n = 0; n < 4; ++n)
                    acc[m][n] = __builtin_amdgcn_mfma_f32_16x16x32_bf16(af[m], bfr[n], acc[m][n], 0, 0, 0);
            __builtin_amdgcn_s_setprio(0);
        }

        __syncthreads();
        if (t + 1 < NT) {
            if (t + 2 < NT) asm volatile("s_waitcnt vmcnt(6)" ::: "memory");
            else            asm volatile("s_waitcnt vmcnt(0)" ::: "memory");
            __syncthreads();
        }
    }
#undef STAGE_A
#undef STAGE_B

    const int ofmt = (mode == 1) ? *flag : 0;
    const float SCQ = 0.18033688011112042f;

#pragma unroll
    for (int n = 0; n < 4; ++n) {
        const int colw = n0 + wn * 64 + n * 16 + l4;
        const float bv = bias[colw];
#pragma unroll
        for (int m = 0; m < 4; ++m) {
            const int mb = m0 + wm * 64 + m * 16 + quad * 4;
            if (mode == 0) {
                const int bb = mb >> 11, t0 = mb & 2047;
                const int h = colw >> 6, d = colw & 63;
                if (which == 2) {
                    u16x4 pk;
#pragma unroll
                    for (int reg = 0; reg < 4; ++reg) pk[reg] = f2bf(acc[m][n][reg] + bv);
                    *(u16x4*)&out[((size_t)(bb * 16 + h) * 64 + d) * 2048 + t0] = pk;
                } else {
                    const float s = (which == 0) ? SCQ : 1.0f;
#pragma unroll
                    for (int reg = 0; reg < 4; ++reg)
                        out[(size_t)((bb * 16 + h) * 2048 + (t0 + reg)) * 64 + d] =
                            f2bf((acc[m][n][reg] + bv) * s);
                }
            } else if (ofmt) {
#pragma unroll
                for (int reg = 0; reg < 4; ++reg)
                    ((float*)out)[(size_t)(mb + reg) * DM + colw] = acc[m][n][reg] + bv;
            } else {
#pragma unroll
                for (int reg = 0; reg < 4; ++reg)
                    out[(size_t)(mb + reg) * DM + colw] = f2bf(acc[m][n][reg] + bv);
            }
        }
    }
}

// ---------------------------------------------------------------------------
// Flash attention v7 (round-9 proven, unchanged): G=4 q-tiles, hoisted kf/vf,
// Pl[4], diag-only masking, K/V LDS dbuf, SCQ folded into Q, exp2_native,
// MFMA rowsums via all-ones B.
// ---------------------------------------------------------------------------
#define LSTR 72

__global__ __launch_bounds__(256, 2) void attn4(
    const u16* __restrict__ Qb, const u16* __restrict__ Kb, const u16* __restrict__ VT,
    const unsigned char* __restrict__ pad,
    u16* __restrict__ Y)
{
    __shared__ u16 Klds[2][64 * LSTR];
    __shared__ u16 Vtl [2][64 * LSTR];
    __shared__ u16 Pl  [4][64 * LSTR];
    __shared__ unsigned char padl[2][64];

    const int nb = blockIdx.y;           // 0..7
    const int bh = blockIdx.x;           // 0..63 -> XCD = bh % 8
    const int b = bh >> 4, h = bh & 15;
    const u16* Qp  = Qb + (size_t)bh * (Tq * 64);
    const u16* Kp  = Kb + (size_t)bh * (Tq * 64);
    const u16* VTp = VT + (size_t)bh * (64 * Tq);

    const int tid = threadIdx.x;
    const int w = tid >> 6, lane = tid & 63;
    const int l4 = lane & 15, quad = lane >> 4;

    const int qt[4] = { nb, nb + 8, 23 - nb, 31 - nb };   // ascending

    bf16x8 qf[4][2];
#pragma unroll
    for (int g = 0; g < 4; ++g) {
        const u16* r = Qp + (size_t)(qt[g] * 64 + w * 16 + l4) * 64 + quad * 8;
        qf[g][0] = *(const bf16x8*)r;
        qf[g][1] = *(const bf16x8*)(r + 32);
    }

    bf16x8 ones;
#pragma unroll
    for (int e = 0; e < 8; ++e) ones[e] = (__bf16)1.0f;

    f32x4 o[4][4] = {};
    f32x4 ls[4] = {};

    const int srow = tid >> 2;
    const int sc   = (tid & 3) * 16;

    u16x8 kr0, kr1, vr0, vr1; unsigned char pr = 0;
    {
        const u16* kg = Kp + (size_t)srow * 64 + sc;
        kr0 = *(const u16x8*)kg; kr1 = *(const u16x8*)(kg + 8);
        const u16* vg = VTp + (size_t)srow * Tq + sc;
        vr0 = *(const u16x8*)vg; vr1 = *(const u16x8*)(vg + 8);
        if (tid < 64) pr = pad[(size_t)b * Tq + tid];
    }
    *(u16x8*)&Klds[0][srow * LSTR + sc]     = kr0;
    *(u16x8*)&Klds[0][srow * LSTR + sc + 8] = kr1;
    *(u16x8*)&Vtl [0][srow * LSTR + sc]     = vr0;
    *(u16x8*)&Vtl [0][srow * LSTR + sc + 8] = vr1;
    if (tid < 64) padl[0][tid] = pr;

    const int ktmax = qt[3];

    for (int kt = 0; kt <= ktmax; ++kt) {
        const int cur = kt & 1;
        const int k0 = kt * 64;
        __syncthreads();
        if (kt < ktmax) {
            const u16* kg = Kp + (size_t)(k0 + 64 + srow) * 64 + sc;
            kr0 = *(const u16x8*)kg; kr1 = *(const u16x8*)(kg + 8);
            const u16* vg = VTp + (size_t)srow * Tq + k0 + 64 + sc;
            vr0 = *(const u16x8*)vg; vr1 = *(const u16x8*)(vg + 8);
            if (tid < 64) pr = pad[(size_t)b * Tq + k0 + 64 + tid];
        }

        const bool anypad = __any((int)(padl[cur][lane] != 0));

        bf16x8 kf[2][4];
#pragma unroll
        for (int c = 0; c < 2; ++c)
#pragma unroll
            for (int n = 0; n < 4; ++n)
                kf[c][n] = *(const bf16x8*)&Klds[cur][(n * 16 + l4) * LSTR + c * 32 + quad * 8];

#pragma unroll
        for (int g = 0; g < 4; ++g) {
            if (kt > qt[g]) continue;
            f32x4 sacc[4] = {};
            __builtin_amdgcn_s_setprio(1);
#pragma unroll
            for (int c = 0; c < 2; ++c)
#pragma unroll
                for (int n = 0; n < 4; ++n)
                    sacc[n] = __builtin_amdgcn_mfma_f32_16x16x32_bf16(qf[g][c], kf[c][n], sacc[n], 0, 0, 0);
            __builtin_amdgcn_s_setprio(0);
            u16* Pg = &Pl[g][0];
            if (kt == qt[g] || anypad) {
                bool pm[4];
#pragma unroll
                for (int n = 0; n < 4; ++n) pm[n] = (padl[cur][n * 16 + l4] != 0);
                const int qr = qt[g] * 64 + w * 16 + quad * 4;
#pragma unroll
                for (int r = 0; r < 4; ++r) {
#pragma unroll
                    for (int n = 0; n < 4; ++n) {
                        const int kgi = k0 + n * 16 + l4;
                        const bool msk = (kgi > qr + r) || pm[n];
                        const float p = msk ? 0.0f : exp2_native(sacc[n][r]);
                        *(__bf16*)&Pg[(w * 16 + quad * 4 + r) * LSTR + n * 16 + l4] = (__bf16)p;
                    }
                }
            } else {
#pragma unroll
                for (int r = 0; r < 4; ++r) {
#pragma unroll
                    for (int n = 0; n < 4; ++n) {
                        const float p = exp2_native(sacc[n][r]);
                        *(__bf16*)&Pg[(w * 16 + quad * 4 + r) * LSTR + n * 16 + l4] = (__bf16)p;
                    }
                }
            }
        }

        bf16x8 vf[2][4];
#pragma unroll
        for (int c = 0; c < 2; ++c)
#pragma unroll
            for (int t = 0; t < 4; ++t)
                vf[c][t] = *(const bf16x8*)&Vtl[cur][(t * 16 + l4) * LSTR + c * 32 + quad * 8];

#pragma unroll
        for (int g = 0; g < 4; ++g) {
            if (kt > qt[g]) continue;
            __builtin_amdgcn_s_setprio(1);
#pragma unroll
            for (int c = 0; c < 2; ++c) {
                bf16x8 pf = *(const bf16x8*)&Pl[g][(w * 16 + l4) * LSTR + c * 32 + quad * 8];
#pragma unroll
                for (int t = 0; t < 4; ++t)
                    o[g][t] = __builtin_amdgcn_mfma_f32_16x16x32_bf16(pf, vf[c][t], o[g][t], 0, 0, 0);
                ls[g] = __builtin_amdgcn_mfma_f32_16x16x32_bf16(pf, ones, ls[g], 0, 0, 0);
            }
            __builtin_amdgcn_s_setprio(0);
        }

        if (kt < ktmax) {
            *(u16x8*)&Klds[cur ^ 1][srow * LSTR + sc]     = kr0;
            *(u16x8*)&Klds[cur ^ 1][srow * LSTR + sc + 8] = kr1;
            *(u16x8*)&Vtl [cur ^ 1][srow * LSTR + sc]     = vr0;
            *(u16x8*)&Vtl [cur ^ 1][srow * LSTR + sc + 8] = vr1;
            if (tid < 64) padl[cur ^ 1][tid] = pr;
        }
    }

#pragma unroll
    for (int g = 0; g < 4; ++g)
#pragma unroll
        for (int r = 0; r < 4; ++r) {
            const float inv = 1.0f / ls[g][r];
            u16* y = Y + (size_t)(b * Tq + (qt[g] * 64 + w * 16 + quad * 4 + r)) * DM + h * 64;
#pragma unroll
            for (int t = 0; t < 4; ++t)
                *(__bf16*)&y[t * 16 + l4] = (__bf16)(o[g][t][r] * inv);
        }
}

// ---------------------------------------------------------------------------
extern "C" void kernel_launch(void* const* d_in, const int* in_sizes, int n_in,
                              void* d_out, int out_size, void* d_ws, size_t ws_size,
                              hipStream_t stream) {
    const void* x  = d_in[0];
    const unsigned char* pad = (const unsigned char*)d_in[1];
    const void* Wq = d_in[2];
    const void* bq = d_in[3];
    const void* Wk = d_in[4];
    const void* bk = d_in[5];
    const void* Wv = d_in[6];
    const void* bv = d_in[7];
    const void* Wo = d_in[8];
    const void* bo = d_in[9];
    const u16* xs = (const u16*)x;

    const size_t NEL = (size_t)8192 * 1024;
    const size_t WEL = (size_t)1024 * 1024;

    int* flag   = (int*)d_ws;
    u16* base16 = (u16*)((char*)d_ws + 256);
    u16* xc     = base16;                          // canonical x; reused as Yb
    u16* Wc     = base16 + NEL;                    // Wq,Wk,Wv,Wo
    float* bf_  = (float*)(base16 + NEL + 4*WEL);  // 4 x 1024 fp32 biases
    u16* Qb     = (u16*)(bf_ + 4096);
    u16* Kb     = Qb + NEL;
    u16* VT     = Kb + NEL;                        // (B,H,64,T) — written by gemm0
    u16* Yb     = xc;

    cvt_all<<<dim3(6144), 256, 0, stream>>>(x, Wq, Wk, Wv, Wo, bq, bk, bv, bo,
                                            xc, Wc, bf_, xs, flag);

    gemm256q<<<dim3(32, 12), 512, 0, stream>>>(xc, Wc, Wc + WEL, Wc + 2*WEL,
                                               bf_, bf_ + 1024, bf_ + 2048,
                                               Qb, Kb, VT);
    attn4<<<dim3(64, 8), 256, 0, stream>>>(Qb, Kb, VT, pad, Yb);
    gemm256<<<dim3(64, 4), 512, 0, stream>>>(Yb, Wc + 3*WEL, Wc + 3*WEL, Wc + 3*WEL,
                                             bf_ + 3072, bf_ + 3072, bf_ + 3072,
                                             (u16*)d_out, nullptr, nullptr, flag, 1);
}

// Round 11
// 238.935 us; speedup vs baseline: 1.0655x; 1.0655x over previous
//
#include <hip/hip_runtime.h>
#include <stdint.h>
#include <stddef.h>

#define Tq 2048
#define DM 1024

typedef unsigned short u16;
typedef __bf16 bf16x8 __attribute__((ext_vector_type(8)));
typedef float f32x4 __attribute__((ext_vector_type(4)));
typedef unsigned short u16x8 __attribute__((ext_vector_type(8)));
typedef unsigned short u16x4 __attribute__((ext_vector_type(4)));

__device__ __forceinline__ float bf2f(u16 h) {
    union { unsigned int u; float f; } c; c.u = ((unsigned int)h) << 16; return c.f;
}
__device__ __forceinline__ u16 f2bf(float f) {
    union { float f; unsigned int u; } c; c.f = f;
    unsigned int u = c.u;
    return (u16)((u + 0x7fffu + ((u >> 16) & 1u)) >> 16);  // RNE
}

// bare v_exp_f32 (2^x) — exp2f expands to the guarded __ocml sequence.
__device__ __forceinline__ float exp2_native(float x) {
    float r; asm("v_exp_f32 %0, %1" : "=v"(r) : "v"(x)); return r;
}

// async global->LDS, 16B per lane; lds base wave-uniform (HW adds lane*16)
#define GLD(gp, lp) __builtin_amdgcn_global_load_lds(                                  \
        (const __attribute__((address_space(1))) void*)(gp),                           \
        (__attribute__((address_space(3))) void*)(lp), 16, 0, 0)

// ---------------------------------------------------------------------------
// Format sniff (round-3 proven).
// ---------------------------------------------------------------------------
__device__ __forceinline__ int sniff_fp32(const u16* xs) {
    const int lane = threadIdx.x & 63;
    const u16 u = xs[lane];
    const int e = (u >> 7) & 0xFF;
    unsigned long long m = __ballot(e >= 160);
    return __popcll(m) >= 4;
}

__device__ __forceinline__ void cvt_body(const void* src, u16* dst, int i0, int fmt) {
    if (fmt) {
        const float* s = (const float*)src;
        float4 a = *(const float4*)(s + i0);
        float4 b = *(const float4*)(s + i0 + 4);
        u16x8 o;
        o[0] = f2bf(a.x); o[1] = f2bf(a.y); o[2] = f2bf(a.z); o[3] = f2bf(a.w);
        o[4] = f2bf(b.x); o[5] = f2bf(b.y); o[6] = f2bf(b.z); o[7] = f2bf(b.w);
        *(u16x8*)(dst + i0) = o;
    } else {
        *(u16x8*)(dst + i0) = *(const u16x8*)((const u16*)src + i0);
    }
}

// ---------------------------------------------------------------------------
// Fused canonicalization: x (blocks 0..4095) + 4 weights/biases (4096..6143).
// ---------------------------------------------------------------------------
__global__ void cvt_all(const void* __restrict__ x,
                        const void* s0, const void* s1, const void* s2, const void* s3,
                        const void* t0, const void* t1, const void* t2, const void* t3,
                        u16* __restrict__ xc, u16* __restrict__ dstW, float* __restrict__ dstB,
                        const u16* __restrict__ xs, int* flag) {
    const int fmt = sniff_fp32(xs);
    int bx = blockIdx.x;
    if (bx < 4096) {
        if (bx == 0 && threadIdx.x == 0) *flag = fmt;
        const int i0 = (bx * 256 + threadIdx.x) * 8;
        cvt_body(x, xc, i0, fmt);
    } else {
        bx -= 4096;
        const int wsel = bx >> 9;          // 0..3
        const int bi   = bx & 511;
        const void* s = (wsel == 0) ? s0 : (wsel == 1) ? s1 : (wsel == 2) ? s2 : s3;
        u16* d = dstW + (size_t)wsel * (DM * DM);
        const int i0 = (bi * 256 + threadIdx.x) * 8;
        cvt_body(s, d, i0, fmt);
        if (bi == 0) {                     // bias piggybacked
            const void* bs = (wsel == 0) ? t0 : (wsel == 1) ? t1 : (wsel == 2) ? t2 : t3;
            float* db = dstB + (size_t)wsel * DM;
            const int j0 = threadIdx.x * 4;
            if (fmt) {
                *(float4*)(db + j0) = *(const float4*)((const float*)bs + j0);
            } else {
                const u16* ss = (const u16*)bs;
                db[j0+0] = bf2f(ss[j0+0]); db[j0+1] = bf2f(ss[j0+1]);
                db[j0+2] = bf2f(ss[j0+2]); db[j0+3] = bf2f(ss[j0+3]);
            }
        }
    }
}

#define NT 16   // K / 64

// ---------------------------------------------------------------------------
// GEMM v5 (round 11): round-8/9 proven structure (BM=128 x BN=256, BK=64,
// 512 thr / 8 waves, triple-buffered LDS 72 KB, T3 interleave, both-sides
// swizzle = 0 bank conflicts) with the sync FIXED to actually apply T4:
//   * ONE raw s_barrier per K-tile + per-wave counted vmcnt gate, replacing
//     the two __syncthreads (each of which drains vmcnt(0) before s_barrier
//     — round-9 discovery — so the old counted gates were dead code and the
//     loop paid 32 full pipeline drains).
//   * Gate derivation (FIFO-oldest): at iter t, reads need tile t landed;
//     outstanding = tiles t (maybe) and t+1 (6 loads) -> vmcnt(6) leaves
//     only t+1's in flight. vmcnt(0) ONLY at t=NT-1.
//   * Hazard: STAGE at iter t writes buf[(t+2)%3], last read at iter t-1;
//     the top-of-iter barrier separates those readers (their ds_reads retire
//     before their MFMAs, hence before barrier arrival) from these writes.
// Round-10 lesson: the 256x256 acc[8][4] quadrant schedule spills (~42 MB
// scratch, VGPR clamped at 120) — retired. This kernel keeps acc[4][4].
// ---------------------------------------------------------------------------
__global__ __launch_bounds__(512, 1) void gemm256(
    const u16* __restrict__ A,
    const u16* __restrict__ W0, const u16* __restrict__ W1, const u16* __restrict__ W2,
    const float* __restrict__ b0, const float* __restrict__ b1, const float* __restrict__ b2,
    u16* o0, u16* o1, u16* o2,
    const int* __restrict__ flag, int mode)
{
    __shared__ u16 LB[3][24576];   // per buf: A [0,8192) elems (128x64), B [8192,24576) (256x64)

    const int K = DM;
    const int j = blockIdx.y;
    const int which = (mode == 0) ? (j >> 2) : 0;
    const u16* Wp     = (which == 0) ? W0 : (which == 1) ? W1 : W2;
    const float* bias = (which == 0) ? b0 : (which == 1) ? b1 : b2;
    u16* out          = (which == 0) ? o0 : (which == 1) ? o1 : o2;
    const int jn = (mode == 0) ? (j & 3) : j;
    const int m0 = blockIdx.x * 128, n0 = jn * 256;

    const int tid  = threadIdx.x;
    const int w    = tid >> 6, lane = tid & 63;
    const int wm   = w >> 2, wn = w & 3;
    const int l4   = lane & 15, quad = lane >> 4;
    const int rsub = lane >> 3;                       // 0..7
    const int colE = ((lane & 7) ^ rsub) << 3;        // swizzled source column (elems)

#define STAGE_A(kt, bf) do {                                                            \
        const int k0s = (kt) * 64;                                                      \
        _Pragma("unroll")                                                               \
        for (int c = 0; c < 2; ++c) {                                                   \
            const int row = c * 64 + w * 8 + rsub;                                      \
            GLD(A + (size_t)(m0 + row) * K + k0s + colE,                                \
                (char*)&LB[bf][0] + c * 8192 + w * 1024);                               \
        }                                                                               \
        {   const int row = w * 8 + rsub;                                               \
            GLD(Wp + (size_t)(n0 + row) * K + k0s + colE,                               \
                (char*)&LB[bf][0] + 16384 + w * 1024); }                                \
    } while (0)
#define STAGE_B(kt, bf) do {                                                            \
        const int k0s = (kt) * 64;                                                      \
        _Pragma("unroll")                                                               \
        for (int c = 1; c < 4; ++c) {                                                   \
            const int row = c * 64 + w * 8 + rsub;                                      \
            GLD(Wp + (size_t)(n0 + row) * K + k0s + colE,                               \
                (char*)&LB[bf][0] + 16384 + c * 8192 + w * 1024);                       \
        }                                                                               \
    } while (0)

    f32x4 acc[4][4] = {};

    // prologue: stage tiles 0 and 1 (6 loads each); no barrier needed here —
    // the loop's first iteration gates and barriers before any LDS read.
    STAGE_A(0, 0); STAGE_B(0, 0);
    STAGE_A(1, 1); STAGE_B(1, 1);

    for (int t = 0; t < NT; ++t) {
        const int cur = t % 3;
        const int nxt = (t + 2) % 3;
        const u16* Ab = &LB[cur][0];
        const u16* Bb = &LB[cur][8192];
        const int swz = (l4 & 7) << 3;
        const bool pf = (t + 2 < NT);

        // gate: tile t landed (FIFO: <=6 outstanding => newest 6 = tile t+1)
        if (t + 1 < NT) asm volatile("s_waitcnt vmcnt(6)" ::: "memory");
        else            asm volatile("s_waitcnt vmcnt(0)" ::: "memory");
        // barrier: separates iter t-1 readers of buf[nxt] from this iter's
        // STAGE writes into it (raw s_barrier — NOT __syncthreads, which
        // would drain vmcnt(0) and kill the pipeline).
        __builtin_amdgcn_s_barrier();

        if (pf) STAGE_A(t + 2, nxt);
        {
            bf16x8 af[4], bfr[4];
            const int kq = (quad * 8) ^ swz;
#pragma unroll
            for (int m = 0; m < 4; ++m)
                af[m] = *(const bf16x8*)&Ab[(wm * 64 + m * 16 + l4) * 64 + kq];
#pragma unroll
            for (int n = 0; n < 4; ++n)
                bfr[n] = *(const bf16x8*)&Bb[(wn * 64 + n * 16 + l4) * 64 + kq];
            __builtin_amdgcn_s_setprio(1);
#pragma unroll
            for (int m = 0; m < 4; ++m)
#pragma unroll
                for (int n = 0; n < 4; ++n)
                    acc[m][n] = __builtin_amdgcn_mfma_f32_16x16x32_bf16(af[m], bfr[n], acc[m][n], 0, 0, 0);
            __builtin_amdgcn_s_setprio(0);
        }

        if (pf) STAGE_B(t + 2, nxt);
        {
            bf16x8 af[4], bfr[4];
            const int kq = (32 + quad * 8) ^ swz;
#pragma unroll
            for (int m = 0; m < 4; ++m)
                af[m] = *(const bf16x8*)&Ab[(wm * 64 + m * 16 + l4) * 64 + kq];
#pragma unroll
            for (int n = 0; n < 4; ++n)
                bfr[n] = *(const bf16x8*)&Bb[(wn * 64 + n * 16 + l4) * 64 + kq];
            __builtin_amdgcn_s_setprio(1);
#pragma unroll
            for (int m = 0; m < 4; ++m)
#pragma unroll
                for (int n = 0; n < 4; ++n)
                    acc[m][n] = __builtin_amdgcn_mfma_f32_16x16x32_bf16(af[m], bfr[n], acc[m][n], 0, 0, 0);
            __builtin_amdgcn_s_setprio(0);
        }
    }
#undef STAGE_A
#undef STAGE_B

    const int ofmt = (mode == 1) ? *flag : 0;
    const float SCQ = 0.18033688011112042f;    // log2(e)/sqrt(64), folded into Q

#pragma unroll
    for (int n = 0; n < 4; ++n) {
        const int colw = n0 + wn * 64 + n * 16 + l4;
        const float bv = bias[colw];
#pragma unroll
        for (int m = 0; m < 4; ++m) {
            const int mb = m0 + wm * 64 + m * 16 + quad * 4;
            if (mode == 0) {
                const int bb = mb >> 11, t0 = mb & 2047;
                const int h = colw >> 6, d = colw & 63;
                if (which == 2) {
                    // V -> (B,H,64,T) transposed store, 4 consecutive t per 8B
                    u16x4 pk;
#pragma unroll
                    for (int reg = 0; reg < 4; ++reg) pk[reg] = f2bf(acc[m][n][reg] + bv);
                    *(u16x4*)&out[((size_t)(bb * 16 + h) * 64 + d) * 2048 + t0] = pk;
                } else {
                    const float s = (which == 0) ? SCQ : 1.0f;
#pragma unroll
                    for (int reg = 0; reg < 4; ++reg)
                        out[(size_t)((bb * 16 + h) * 2048 + (t0 + reg)) * 64 + d] =
                            f2bf((acc[m][n][reg] + bv) * s);
                }
            } else if (ofmt) {
#pragma unroll
                for (int reg = 0; reg < 4; ++reg)
                    ((float*)out)[(size_t)(mb + reg) * DM + colw] = acc[m][n][reg] + bv;
            } else {
#pragma unroll
                for (int reg = 0; reg < 4; ++reg)
                    out[(size_t)(mb + reg) * DM + colw] = f2bf(acc[m][n][reg] + bv);
            }
        }
    }
}

// ---------------------------------------------------------------------------
// Flash attention v7 (round-9 proven, unchanged): G=4 q-tiles, hoisted kf/vf,
// Pl[4], diag-only masking, K/V LDS dbuf, SCQ folded into Q, exp2_native,
// MFMA rowsums via all-ones B.
// ---------------------------------------------------------------------------
#define LSTR 72

__global__ __launch_bounds__(256, 2) void attn4(
    const u16* __restrict__ Qb, const u16* __restrict__ Kb, const u16* __restrict__ VT,
    const unsigned char* __restrict__ pad,
    u16* __restrict__ Y)
{
    __shared__ u16 Klds[2][64 * LSTR];
    __shared__ u16 Vtl [2][64 * LSTR];
    __shared__ u16 Pl  [4][64 * LSTR];
    __shared__ unsigned char padl[2][64];

    const int nb = blockIdx.y;           // 0..7
    const int bh = blockIdx.x;           // 0..63 -> XCD = bh % 8
    const int b = bh >> 4, h = bh & 15;
    const u16* Qp  = Qb + (size_t)bh * (Tq * 64);
    const u16* Kp  = Kb + (size_t)bh * (Tq * 64);
    const u16* VTp = VT + (size_t)bh * (64 * Tq);

    const int tid = threadIdx.x;
    const int w = tid >> 6, lane = tid & 63;
    const int l4 = lane & 15, quad = lane >> 4;

    const int qt[4] = { nb, nb + 8, 23 - nb, 31 - nb };   // ascending

    bf16x8 qf[4][2];
#pragma unroll
    for (int g = 0; g < 4; ++g) {
        const u16* r = Qp + (size_t)(qt[g] * 64 + w * 16 + l4) * 64 + quad * 8;
        qf[g][0] = *(const bf16x8*)r;
        qf[g][1] = *(const bf16x8*)(r + 32);
    }

    bf16x8 ones;
#pragma unroll
    for (int e = 0; e < 8; ++e) ones[e] = (__bf16)1.0f;

    f32x4 o[4][4] = {};
    f32x4 ls[4] = {};

    const int srow = tid >> 2;
    const int sc   = (tid & 3) * 16;

    u16x8 kr0, kr1, vr0, vr1; unsigned char pr = 0;
    {
        const u16* kg = Kp + (size_t)srow * 64 + sc;
        kr0 = *(const u16x8*)kg; kr1 = *(const u16x8*)(kg + 8);
        const u16* vg = VTp + (size_t)srow * Tq + sc;
        vr0 = *(const u16x8*)vg; vr1 = *(const u16x8*)(vg + 8);
        if (tid < 64) pr = pad[(size_t)b * Tq + tid];
    }
    *(u16x8*)&Klds[0][srow * LSTR + sc]     = kr0;
    *(u16x8*)&Klds[0][srow * LSTR + sc + 8] = kr1;
    *(u16x8*)&Vtl [0][srow * LSTR + sc]     = vr0;
    *(u16x8*)&Vtl [0][srow * LSTR + sc + 8] = vr1;
    if (tid < 64) padl[0][tid] = pr;

    const int ktmax = qt[3];

    for (int kt = 0; kt <= ktmax; ++kt) {
        const int cur = kt & 1;
        const int k0 = kt * 64;
        __syncthreads();
        if (kt < ktmax) {
            const u16* kg = Kp + (size_t)(k0 + 64 + srow) * 64 + sc;
            kr0 = *(const u16x8*)kg; kr1 = *(const u16x8*)(kg + 8);
            const u16* vg = VTp + (size_t)srow * Tq + k0 + 64 + sc;
            vr0 = *(const u16x8*)vg; vr1 = *(const u16x8*)(vg + 8);
            if (tid < 64) pr = pad[(size_t)b * Tq + k0 + 64 + tid];
        }

        const bool anypad = __any((int)(padl[cur][lane] != 0));

        bf16x8 kf[2][4];
#pragma unroll
        for (int c = 0; c < 2; ++c)
#pragma unroll
            for (int n = 0; n < 4; ++n)
                kf[c][n] = *(const bf16x8*)&Klds[cur][(n * 16 + l4) * LSTR + c * 32 + quad * 8];

#pragma unroll
        for (int g = 0; g < 4; ++g) {
            if (kt > qt[g]) continue;
            f32x4 sacc[4] = {};
            __builtin_amdgcn_s_setprio(1);
#pragma unroll
            for (int c = 0; c < 2; ++c)
#pragma unroll
                for (int n = 0; n < 4; ++n)
                    sacc[n] = __builtin_amdgcn_mfma_f32_16x16x32_bf16(qf[g][c], kf[c][n], sacc[n], 0, 0, 0);
            __builtin_amdgcn_s_setprio(0);
            u16* Pg = &Pl[g][0];
            if (kt == qt[g] || anypad) {
                bool pm[4];
#pragma unroll
                for (int n = 0; n < 4; ++n) pm[n] = (padl[cur][n * 16 + l4] != 0);
                const int qr = qt[g] * 64 + w * 16 + quad * 4;
#pragma unroll
                for (int r = 0; r < 4; ++r) {
#pragma unroll
                    for (int n = 0; n < 4; ++n) {
                        const int kgi = k0 + n * 16 + l4;
                        const bool msk = (kgi > qr + r) || pm[n];
                        const float p = msk ? 0.0f : exp2_native(sacc[n][r]);
                        *(__bf16*)&Pg[(w * 16 + quad * 4 + r) * LSTR + n * 16 + l4] = (__bf16)p;
                    }
                }
            } else {
#pragma unroll
                for (int r = 0; r < 4; ++r) {
#pragma unroll
                    for (int n = 0; n < 4; ++n) {
                        const float p = exp2_native(sacc[n][r]);
                        *(__bf16*)&Pg[(w * 16 + quad * 4 + r) * LSTR + n * 16 + l4] = (__bf16)p;
                    }
                }
            }
        }

        bf16x8 vf[2][4];
#pragma unroll
        for (int c = 0; c < 2; ++c)
#pragma unroll
            for (int t = 0; t < 4; ++t)
                vf[c][t] = *(const bf16x8*)&Vtl[cur][(t * 16 + l4) * LSTR + c * 32 + quad * 8];

#pragma unroll
        for (int g = 0; g < 4; ++g) {
            if (kt > qt[g]) continue;
            __builtin_amdgcn_s_setprio(1);
#pragma unroll
            for (int c = 0; c < 2; ++c) {
                bf16x8 pf = *(const bf16x8*)&Pl[g][(w * 16 + l4) * LSTR + c * 32 + quad * 8];
#pragma unroll
                for (int t = 0; t < 4; ++t)
                    o[g][t] = __builtin_amdgcn_mfma_f32_16x16x32_bf16(pf, vf[c][t], o[g][t], 0, 0, 0);
                ls[g] = __builtin_amdgcn_mfma_f32_16x16x32_bf16(pf, ones, ls[g], 0, 0, 0);
            }
            __builtin_amdgcn_s_setprio(0);
        }

        if (kt < ktmax) {
            *(u16x8*)&Klds[cur ^ 1][srow * LSTR + sc]     = kr0;
            *(u16x8*)&Klds[cur ^ 1][srow * LSTR + sc + 8] = kr1;
            *(u16x8*)&Vtl [cur ^ 1][srow * LSTR + sc]     = vr0;
            *(u16x8*)&Vtl [cur ^ 1][srow * LSTR + sc + 8] = vr1;
            if (tid < 64) padl[cur ^ 1][tid] = pr;
        }
    }

#pragma unroll
    for (int g = 0; g < 4; ++g)
#pragma unroll
        for (int r = 0; r < 4; ++r) {
            const float inv = 1.0f / ls[g][r];
            u16* y = Y + (size_t)(b * Tq + (qt[g] * 64 + w * 16 + quad * 4 + r)) * DM + h * 64;
#pragma unroll
            for (int t = 0; t < 4; ++t)
                *(__bf16*)&y[t * 16 + l4] = (__bf16)(o[g][t][r] * inv);
        }
}

// ---------------------------------------------------------------------------
extern "C" void kernel_launch(void* const* d_in, const int* in_sizes, int n_in,
                              void* d_out, int out_size, void* d_ws, size_t ws_size,
                              hipStream_t stream) {
    const void* x  = d_in[0];
    const unsigned char* pad = (const unsigned char*)d_in[1];
    const void* Wq = d_in[2];
    const void* bq = d_in[3];
    const void* Wk = d_in[4];
    const void* bk = d_in[5];
    const void* Wv = d_in[6];
    const void* bv = d_in[7];
    const void* Wo = d_in[8];
    const void* bo = d_in[9];
    const u16* xs = (const u16*)x;

    const size_t NEL = (size_t)8192 * 1024;
    const size_t WEL = (size_t)1024 * 1024;

    int* flag   = (int*)d_ws;
    u16* base16 = (u16*)((char*)d_ws + 256);
    u16* xc     = base16;                          // canonical x; reused as Yb
    u16* Wc     = base16 + NEL;                    // Wq,Wk,Wv,Wo
    float* bf_  = (float*)(base16 + NEL + 4*WEL);  // 4 x 1024 fp32 biases
    u16* Qb     = (u16*)(bf_ + 4096);
    u16* Kb     = Qb + NEL;
    u16* VT     = Kb + NEL;                        // (B,H,64,T) — written by gemm0
    u16* Yb     = xc;

    cvt_all<<<dim3(6144), 256, 0, stream>>>(x, Wq, Wk, Wv, Wo, bq, bk, bv, bo,
                                            xc, Wc, bf_, xs, flag);

    gemm256<<<dim3(64, 12), 512, 0, stream>>>(xc, Wc, Wc + WEL, Wc + 2*WEL,
                                              bf_, bf_ + 1024, bf_ + 2048,
                                              Qb, Kb, VT, flag, 0);
    attn4<<<dim3(64, 8), 256, 0, stream>>>(Qb, Kb, VT, pad, Yb);
    gemm256<<<dim3(64, 4), 512, 0, stream>>>(Yb, Wc + 3*WEL, Wc + 3*WEL, Wc + 3*WEL,
                                             bf_ + 3072, bf_ + 3072, bf_ + 3072,
                                             (u16*)d_out, nullptr, nullptr, flag, 1);
}